// Round 9
// baseline (92.564 us; speedup 1.0000x reference)
//
#include <hip/hip_runtime.h>

// Problem constants: B=32, N=2048, D=512, O=2
#define BB 32
#define NN 2048
#define DD 512
#define CC 32            // chunks along N
#define LL 64            // steps per chunk
#define DQ 128           // float4 lanes per row (512/4)

typedef float vf4 __attribute__((ext_vector_type(4)));

// Recurrence: m0'=a0*m0+g ; m1'=a1*m1+m0' ; w'=e*w + c0*g + c1*m0' + c2*m1'
// Chunk matrix P = prod M_t (lower-tri, gate-only, 6 scalars).
// Each 256-thread block processes TWO chunks: waves 0-1 -> chunk 2bx,
// waves 2-3 -> chunk 2bx+1 (gate addresses remain wave-uniform).

// ---------------- Pass 1: per-chunk local scan (zero init) + chunk matrix ----------------
__global__ __launch_bounds__(256) void pass1_local(
    const float* __restrict__ grad,   // (B,N,D)
    const float* __restrict__ am,     // (2,B,N)
    const float* __restrict__ cm,     // (3,B,N)
    const float* __restrict__ dec,    // (B,N)
    float* __restrict__ Mtot,         // (B,CC,6)
    float* __restrict__ local_end)    // (B,CC,3,D)
{
    const int half = threadIdx.x >> 7;        // which chunk of the pair
    const int lane = threadIdx.x & 127;       // float4 lane; d = 4*lane
    const int c = (blockIdx.x << 1) | half;
    const int b = blockIdx.y;
    const vf4* g4 = (const vf4*)grad;

    const float* a0p = am + (size_t)(0 * BB + b) * NN;
    const float* a1p = am + (size_t)(1 * BB + b) * NN;
    const float* c0p = cm + (size_t)(0 * BB + b) * NN;
    const float* c1p = cm + (size_t)(1 * BB + b) * NN;
    const float* c2p = cm + (size_t)(2 * BB + b) * NN;
    const float* dp  = dec + (size_t)b * NN;

    vf4 m0 = {0.f, 0.f, 0.f, 0.f}, m1 = m0, w = m0;
    float p00 = 1.f, p10 = 0.f, p11 = 1.f, p20 = 0.f, p21 = 0.f, p22 = 1.f;

    const int t0 = c * LL;
    #pragma unroll 8
    for (int t = t0; t < t0 + LL; ++t) {
        const float a0 = a0p[t], a1 = a1p[t];
        const float c0 = c0p[t], c1 = c1p[t], c2 = c2p[t];
        const float e  = 1.0f - dp[t];
        const vf4 g = g4[(size_t)(b * NN + t) * DQ + lane];

        m0 = a0 * m0 + g;
        m1 = a1 * m1 + m0;
        w  = e * w + c0 * g + c1 * m0 + c2 * m1;

        const float k0 = (c1 + c2) * a0;
        const float k1 = c2 * a1;
        const float n00 = a0 * p00;
        const float n10 = fmaf(a0, p00, a1 * p10);
        const float n11 = a1 * p11;
        const float n20 = fmaf(k0, p00, fmaf(k1, p10, e * p20));
        const float n21 = fmaf(k1, p11, e * p21);
        const float n22 = e * p22;
        p00 = n00; p10 = n10; p11 = n11; p20 = n20; p21 = n21; p22 = n22;
    }

    vf4* le = (vf4*)local_end;
    const size_t base = (size_t)(b * CC + c) * 3 * DQ;
    le[base + 0 * DQ + lane] = m0;
    le[base + 1 * DQ + lane] = m1;
    le[base + 2 * DQ + lane] = w;

    if (lane == 0) {
        float* mt = Mtot + (size_t)(b * CC + c) * 6;
        mt[0] = p00; mt[1] = p10; mt[2] = p11;
        mt[3] = p20; mt[4] = p21; mt[5] = p22;
    }
}

// ---------------- Pass 2 (fused): redundant carry prefix + exact rescan ----------------
__global__ __launch_bounds__(256) void pass3_fused(
    const float* __restrict__ grad,
    const float* __restrict__ am,
    const float* __restrict__ cm,
    const float* __restrict__ dec,
    const float* __restrict__ Wt,        // (B,D)
    const float* __restrict__ lm,        // (2,B,D)
    const float* __restrict__ Mtot,      // (B,CC,6)
    const float* __restrict__ local_end, // (B,CC,3,D)
    float* __restrict__ out)             // update (B,N+1,D) then next_last (2,B,D)
{
    const int half = threadIdx.x >> 7;
    const int lane = threadIdx.x & 127;
    const int c = (blockIdx.x << 1) | half;
    const int b = blockIdx.y;

    // ---- initial global state ----
    vf4 s0 = ((const vf4*)lm)[(size_t)(0 * BB + b) * DQ + lane];
    vf4 s1 = ((const vf4*)lm)[(size_t)(1 * BB + b) * DQ + lane];
    vf4 s2 = ((const vf4*)Wt)[(size_t)b * DQ + lane];

    // ---- redundant carry prefix over chunks 0..c-1 (loads independent, L2/L3-hot) ----
    const vf4* le = (const vf4*)local_end;
    for (int cc = 0; cc < c; ++cc) {
        const float* mt = Mtot + (size_t)(b * CC + cc) * 6;
        const float p00 = mt[0], p10 = mt[1], p11 = mt[2];
        const float p20 = mt[3], p21 = mt[4], p22 = mt[5];

        const size_t base = (size_t)(b * CC + cc) * 3 * DQ;
        const vf4 l0 = le[base + 0 * DQ + lane];
        const vf4 l1 = le[base + 1 * DQ + lane];
        const vf4 l2 = le[base + 2 * DQ + lane];

        const vf4 n0 = p00 * s0 + l0;
        const vf4 n1 = p10 * s0 + p11 * s1 + l1;
        const vf4 n2 = p20 * s0 + p21 * s1 + p22 * s2 + l2;
        s0 = n0; s1 = n1; s2 = n2;
    }

    vf4* out4 = (vf4*)out;
    if (c == 0) {
        // update[b][0][:] = W_t (s2 here)
        out4[(size_t)(b * (NN + 1)) * DQ + lane] = s2;
    }

    // ---- exact rescan from carry; stream update with plain stores ----
    const float* a0p = am + (size_t)(0 * BB + b) * NN;
    const float* a1p = am + (size_t)(1 * BB + b) * NN;
    const float* c0p = cm + (size_t)(0 * BB + b) * NN;
    const float* c1p = cm + (size_t)(1 * BB + b) * NN;
    const float* c2p = cm + (size_t)(2 * BB + b) * NN;
    const float* dp  = dec + (size_t)b * NN;

    const vf4* g4 = (const vf4*)grad;
    vf4 m0 = s0, m1 = s1, w = s2;

    const int t0 = c * LL;
    #pragma unroll 8
    for (int t = t0; t < t0 + LL; ++t) {
        const float a0 = a0p[t], a1 = a1p[t];
        const float c0 = c0p[t], c1 = c1p[t], c2 = c2p[t];
        const float e  = 1.0f - dp[t];
        // NT load: last use of grad, keep L2 for the write stream
        const vf4 g = __builtin_nontemporal_load(&g4[(size_t)(b * NN + t) * DQ + lane]);

        m0 = a0 * m0 + g;
        m1 = a1 * m1 + m0;
        w  = e * w + c0 * g + c1 * m0 + c2 * m1;

        // plain store: write-combine through L2 (6.9 TB/s fill-path)
        out4[(size_t)(b * (NN + 1) + t + 1) * DQ + lane] = w;
    }

    if (c == CC - 1) {
        // next_last_momentum (2,B,D) = final (m0, m1)
        const size_t nl = (size_t)BB * (NN + 1) * DQ;
        out4[nl + (size_t)(0 * BB + b) * DQ + lane] = m0;
        out4[nl + (size_t)(1 * BB + b) * DQ + lane] = m1;
    }
}

extern "C" void kernel_launch(void* const* d_in, const int* in_sizes, int n_in,
                              void* d_out, int out_size, void* d_ws, size_t ws_size,
                              hipStream_t stream) {
    const float* Wt   = (const float*)d_in[0];   // (B,D)
    // d_in[1] = x_t, unused
    const float* grad = (const float*)d_in[2];   // (B,N,D)
    const float* lm   = (const float*)d_in[3];   // (2,B,D)
    const float* am   = (const float*)d_in[4];   // (2,B,N,1)
    const float* cm   = (const float*)d_in[5];   // (3,B,N)
    const float* dec  = (const float*)d_in[6];   // (B,N,1)
    float* out = (float*)d_out;

    // ws: Mtot 24KB | local_end 6.3MB
    char* ws = (char*)d_ws;
    float* Mtot      = (float*)ws;
    float* local_end = (float*)(ws + (size_t)BB * CC * 6 * sizeof(float));

    dim3 grid(CC / 2, BB);   // 2 chunks per block
    pass1_local<<<grid, 256, 0, stream>>>(grad, am, cm, dec, Mtot, local_end);
    pass3_fused<<<grid, 256, 0, stream>>>(grad, am, cm, dec, Wt, lm, Mtot,
                                          local_end, out);
}

// Round 10
// 74.402 us; speedup vs baseline: 1.2441x; 1.2441x over previous
//
#include <hip/hip_runtime.h>

// Problem constants: B=32, N=2048, D=512, O=2
#define BB 32
#define NN 2048
#define DD 512
#define CC 32            // chunks along N
#define LL 64            // steps per chunk
#define DQ 128           // float4 lanes per row (512/4)

typedef float vf4 __attribute__((ext_vector_type(4)));

// Recurrence: m0'=a0*m0+g ; m1'=a1*m1+m0' ; w'=e*w + c0*g + c1*m0' + c2*m1'
// Chunk matrix P = prod M_t (lower-tri, gate-only, 6 scalars).
// 256-thread block = TWO chunks (waves 0-1 -> chunk 2bx, waves 2-3 -> 2bx+1).
// The per-half chunk id is forced into an SGPR via readfirstlane so the six
// gate streams stay scalar (s_load) instead of divergent VMEM.

// ---------------- Pass 1: per-chunk local scan (zero init) + chunk matrix ----------------
__global__ __launch_bounds__(256) void pass1_local(
    const float* __restrict__ grad,   // (B,N,D)
    const float* __restrict__ am,     // (2,B,N)
    const float* __restrict__ cm,     // (3,B,N)
    const float* __restrict__ dec,    // (B,N)
    float* __restrict__ Mtot,         // (B,CC,6)
    float* __restrict__ local_end)    // (B,CC,3,D)
{
    const int half = __builtin_amdgcn_readfirstlane(threadIdx.x >> 7); // SGPR
    const int lane = threadIdx.x & 127;       // float4 lane; d = 4*lane
    const int c = (blockIdx.x << 1) | half;   // SGPR (uniform operands)
    const int b = blockIdx.y;
    const vf4* g4 = (const vf4*)grad;

    const float* a0p = am + (size_t)(0 * BB + b) * NN;
    const float* a1p = am + (size_t)(1 * BB + b) * NN;
    const float* c0p = cm + (size_t)(0 * BB + b) * NN;
    const float* c1p = cm + (size_t)(1 * BB + b) * NN;
    const float* c2p = cm + (size_t)(2 * BB + b) * NN;
    const float* dp  = dec + (size_t)b * NN;

    vf4 m0 = {0.f, 0.f, 0.f, 0.f}, m1 = m0, w = m0;
    float p00 = 1.f, p10 = 0.f, p11 = 1.f, p20 = 0.f, p21 = 0.f, p22 = 1.f;

    const int t0 = c * LL;
    #pragma unroll 8
    for (int t = t0; t < t0 + LL; ++t) {
        const float a0 = a0p[t], a1 = a1p[t];
        const float c0 = c0p[t], c1 = c1p[t], c2 = c2p[t];
        const float e  = 1.0f - dp[t];
        const vf4 g = g4[(size_t)(b * NN + t) * DQ + lane];

        m0 = a0 * m0 + g;
        m1 = a1 * m1 + m0;
        w  = e * w + c0 * g + c1 * m0 + c2 * m1;

        const float k0 = (c1 + c2) * a0;
        const float k1 = c2 * a1;
        const float n00 = a0 * p00;
        const float n10 = fmaf(a0, p00, a1 * p10);
        const float n11 = a1 * p11;
        const float n20 = fmaf(k0, p00, fmaf(k1, p10, e * p20));
        const float n21 = fmaf(k1, p11, e * p21);
        const float n22 = e * p22;
        p00 = n00; p10 = n10; p11 = n11; p20 = n20; p21 = n21; p22 = n22;
    }

    vf4* le = (vf4*)local_end;
    const size_t base = (size_t)(b * CC + c) * 3 * DQ;
    le[base + 0 * DQ + lane] = m0;
    le[base + 1 * DQ + lane] = m1;
    le[base + 2 * DQ + lane] = w;

    if (lane == 0) {
        float* mt = Mtot + (size_t)(b * CC + c) * 6;
        mt[0] = p00; mt[1] = p10; mt[2] = p11;
        mt[3] = p20; mt[4] = p21; mt[5] = p22;
    }
}

// ---------------- Pass 2 (fused): redundant carry prefix + exact rescan ----------------
__global__ __launch_bounds__(256) void pass3_fused(
    const float* __restrict__ grad,
    const float* __restrict__ am,
    const float* __restrict__ cm,
    const float* __restrict__ dec,
    const float* __restrict__ Wt,        // (B,D)
    const float* __restrict__ lm,        // (2,B,D)
    const float* __restrict__ Mtot,      // (B,CC,6)
    const float* __restrict__ local_end, // (B,CC,3,D)
    float* __restrict__ out)             // update (B,N+1,D) then next_last (2,B,D)
{
    const int half = __builtin_amdgcn_readfirstlane(threadIdx.x >> 7); // SGPR
    const int lane = threadIdx.x & 127;
    const int c = (blockIdx.x << 1) | half;
    const int b = blockIdx.y;

    // ---- initial global state ----
    vf4 s0 = ((const vf4*)lm)[(size_t)(0 * BB + b) * DQ + lane];
    vf4 s1 = ((const vf4*)lm)[(size_t)(1 * BB + b) * DQ + lane];
    vf4 s2 = ((const vf4*)Wt)[(size_t)b * DQ + lane];

    // ---- redundant carry prefix over chunks 0..c-1 (loads independent, L2-hot) ----
    const vf4* le = (const vf4*)local_end;
    for (int cc = 0; cc < c; ++cc) {
        const float* mt = Mtot + (size_t)(b * CC + cc) * 6;
        const float p00 = mt[0], p10 = mt[1], p11 = mt[2];
        const float p20 = mt[3], p21 = mt[4], p22 = mt[5];

        const size_t base = (size_t)(b * CC + cc) * 3 * DQ;
        const vf4 l0 = le[base + 0 * DQ + lane];
        const vf4 l1 = le[base + 1 * DQ + lane];
        const vf4 l2 = le[base + 2 * DQ + lane];

        const vf4 n0 = p00 * s0 + l0;
        const vf4 n1 = p10 * s0 + p11 * s1 + l1;
        const vf4 n2 = p20 * s0 + p21 * s1 + p22 * s2 + l2;
        s0 = n0; s1 = n1; s2 = n2;
    }

    vf4* out4 = (vf4*)out;
    if (c == 0) {
        // update[b][0][:] = W_t (s2 here)
        __builtin_nontemporal_store(s2, &out4[(size_t)(b * (NN + 1)) * DQ + lane]);
    }

    // ---- exact rescan from carry; NT-stream update (no L2/L3 allocation) ----
    const float* a0p = am + (size_t)(0 * BB + b) * NN;
    const float* a1p = am + (size_t)(1 * BB + b) * NN;
    const float* c0p = cm + (size_t)(0 * BB + b) * NN;
    const float* c1p = cm + (size_t)(1 * BB + b) * NN;
    const float* c2p = cm + (size_t)(2 * BB + b) * NN;
    const float* dp  = dec + (size_t)b * NN;

    const vf4* g4 = (const vf4*)grad;
    vf4 m0 = s0, m1 = s1, w = s2;

    const int t0 = c * LL;
    #pragma unroll 8
    for (int t = t0; t < t0 + LL; ++t) {
        const float a0 = a0p[t], a1 = a1p[t];
        const float c0 = c0p[t], c1 = c1p[t], c2 = c2p[t];
        const float e  = 1.0f - dp[t];
        const vf4 g = g4[(size_t)(b * NN + t) * DQ + lane];   // plain load

        m0 = a0 * m0 + g;
        m1 = a1 * m1 + m0;
        w  = e * w + c0 * g + c1 * m0 + c2 * m1;

        __builtin_nontemporal_store(
            w, &out4[(size_t)(b * (NN + 1) + t + 1) * DQ + lane]);
    }

    if (c == CC - 1) {
        // next_last_momentum (2,B,D) = final (m0, m1)
        const size_t nl = (size_t)BB * (NN + 1) * DQ;
        __builtin_nontemporal_store(m0, &out4[nl + (size_t)(0 * BB + b) * DQ + lane]);
        __builtin_nontemporal_store(m1, &out4[nl + (size_t)(1 * BB + b) * DQ + lane]);
    }
}

extern "C" void kernel_launch(void* const* d_in, const int* in_sizes, int n_in,
                              void* d_out, int out_size, void* d_ws, size_t ws_size,
                              hipStream_t stream) {
    const float* Wt   = (const float*)d_in[0];   // (B,D)
    // d_in[1] = x_t, unused
    const float* grad = (const float*)d_in[2];   // (B,N,D)
    const float* lm   = (const float*)d_in[3];   // (2,B,D)
    const float* am   = (const float*)d_in[4];   // (2,B,N,1)
    const float* cm   = (const float*)d_in[5];   // (3,B,N)
    const float* dec  = (const float*)d_in[6];   // (B,N,1)
    float* out = (float*)d_out;

    // ws: Mtot 24KB | local_end 6.3MB
    char* ws = (char*)d_ws;
    float* Mtot      = (float*)ws;
    float* local_end = (float*)(ws + (size_t)BB * CC * 6 * sizeof(float));

    dim3 grid(CC / 2, BB);   // 2 chunks per block
    pass1_local<<<grid, 256, 0, stream>>>(grad, am, cm, dec, Mtot, local_end);
    pass3_fused<<<grid, 256, 0, stream>>>(grad, am, cm, dec, Wt, lm, Mtot,
                                          local_end, out);
}